// Round 10
// baseline (436.325 us; speedup 1.0000x reference)
//
#include <hip/hip_runtime.h>
#include <stdint.h>

// Causal attention, B=4, SQ=SK=2048, D=1024, fp32 in/out, bf16 MFMA compute.
// R10 = R9 with K ALSO panel-transformed -> direct global->VGPR (coalesced),
//      glds/Kc deleted. LDS 75KB -> 2 blocks/CU (16 waves/CU). Same kv-split
//      + combine + swapped-QK^T + register softmax as R7/R9.
// Layouts: Kp[b][kv/16][d/8][kv%16][8d]  (A-frag load = 1KB/wave contiguous)
//          Vp[b][sk/32][d][sk%32]        (PV frag load = 1KB/wave contiguous)

#define B_SZ 4
#define SEQ 2048
#define DIM 1024
#define QBLK 32
#define KVBLK 128
#define NWAVES 8
#define PAN  ((size_t)DIM * 32)   // elems per 32-kv V panel
#define KPAN ((size_t)DIM * 16)   // elems per 16-kv K panel

typedef __bf16 bf16x8 __attribute__((ext_vector_type(8)));
typedef unsigned short u16x8 __attribute__((ext_vector_type(8)));
typedef unsigned short u16x4 __attribute__((ext_vector_type(4)));
typedef float f32x4 __attribute__((ext_vector_type(4)));

__device__ __forceinline__ unsigned short f2bf(float f) {
  union { float f; uint32_t u; } c; c.f = f;
  uint32_t u = c.u;
  u += 0x7FFFu + ((u >> 16) & 1u);   // RNE
  return (unsigned short)(u >> 16);
}

// K[b][kv][d] fp32 -> Kp[b][kv/16][d/8][kv%16][8] bf16
__global__ void transpose_k_kernel(const float* __restrict__ in,
                                   unsigned short* __restrict__ out) {
  const int b   = blockIdx.z;
  const int kv0 = blockIdx.y * 16;
  const int d0  = blockIdx.x * 128;
  const int t   = threadIdx.x;          // 256
  const int kvl = t >> 4;               // 0..15
  const int uu  = t & 15;               // 0..15 d-units
  const int d   = d0 + uu * 8;
  const float* src = in + (size_t)b * SEQ * DIM + (size_t)(kv0 + kvl) * DIM + d;
  f32x4 a = *(const f32x4*)(src);
  f32x4 c = *(const f32x4*)(src + 4);
  u16x8 pk;
#pragma unroll
  for (int j = 0; j < 4; ++j) { pk[j] = f2bf(a[j]); pk[4 + j] = f2bf(c[j]); }
  *(u16x8*)(out + (size_t)b * SEQ * DIM + (size_t)blockIdx.y * KPAN
            + (size_t)(d >> 3) * 128 + kvl * 8) = pk;
}

// V[b][sk][d] fp32 -> Vp[b][sk/32][d][sk%32] bf16 (panel-transposed)
__global__ void transpose_v_kernel(const float* __restrict__ in,
                                   unsigned short* __restrict__ out) {
  __shared__ unsigned short tile[32][33];
  const int b  = blockIdx.z;
  const int s0 = blockIdx.y * 32;
  const int d0 = blockIdx.x * 32;
  const int t  = threadIdx.x;
  const int r  = t >> 3;
  const int c4 = (t & 7) * 4;
  const size_t ibase = (size_t)b * SEQ * DIM;
  const size_t obase = (size_t)b * DIM * SEQ;

  f32x4 v = *(const f32x4*)(in + ibase + (size_t)(s0 + r) * DIM + d0 + c4);
#pragma unroll
  for (int j = 0; j < 4; ++j) tile[r][c4 + j] = f2bf(v[j]);
  __syncthreads();
  u16x4 o;
#pragma unroll
  for (int j = 0; j < 4; ++j) o[j] = tile[c4 + j][r];
  *(u16x4*)(out + obase + (size_t)(s0 >> 5) * PAN + (size_t)(d0 + r) * 32 + c4) = o;
}

__device__ __forceinline__ int imin(int a, int b) { return a < b ? a : b; }

__global__ __launch_bounds__(512, 4) void attn_part(
    const float* __restrict__ Qf, const unsigned short* __restrict__ Kp,
    const unsigned short* __restrict__ Vp, float* __restrict__ Out,
    float* __restrict__ Opart, float* __restrict__ Ml, int mode) {
  const int tid  = threadIdx.x;
  const int lane = tid & 63;
  const int wv   = tid >> 6;        // 0..7: kv strip (QK) and 128-wide D slice (PV)
  const int g    = lane >> 4;       // 0..3
  const int i16  = lane & 15;
  const int swz  = i16 & 7;

  // ---- work-item decode: chunk-major, XCD-affine, heavy-first ----
  const int IPX = (mode == 2) ? 80 : (mode == 1) ? 48 : 32;
  const int IPB = (mode == 2) ? 160 : (mode == 1) ? 96 : 64;
  const int item  = (blockIdx.x & 7) * IPX + (blockIdx.x >> 3);
  const int batch = item / IPB;
  const int r     = IPB - 1 - (item % IPB);

  int qt, kvlo, kvhi, slot;
  if (mode == 2) {
    if (r < 16)       { qt = r;             kvlo = 0;    kvhi = 32 * qt + 32;             slot = -1; }
    else if (r < 64)  { qt = r;             kvlo = 0;    kvhi = 512;                      slot = batch * 144 + (r - 16); }
    else if (r < 112) { qt = 16 + (r - 64); kvlo = 512;  kvhi = imin(1024, 32 * qt + 32); slot = batch * 144 + (r - 16); }
    else if (r < 144) { qt = 32 + (r - 112); kvlo = 1024; kvhi = imin(1536, 32 * qt + 32); slot = batch * 144 + (r - 16); }
    else              { qt = 48 + (r - 144); kvlo = 1536; kvhi = 32 * qt + 32;            slot = batch * 144 + (r - 16); }
  } else if (mode == 1) {
    if (r < 32)       { qt = r;             kvlo = 0;    kvhi = 32 * qt + 32;  slot = -1; }
    else if (r < 64)  { qt = 32 + (r - 32); kvlo = 0;    kvhi = 1024;          slot = batch * 64 + (r - 32); }
    else              { qt = 32 + (r - 64); kvlo = 1024; kvhi = 32 * qt + 32;  slot = batch * 64 + (r - 32); }
  } else {
    qt = r; kvlo = 0; kvhi = 32 * qt + 32; slot = -1;
  }

  const int q0 = qt * QBLK;
  const size_t boff = (size_t)batch * SEQ * DIM;

  __shared__ __align__(16) unsigned short Qs[QBLK * 1024];   // 64 KB swizzled
  __shared__ __align__(16) unsigned short Pl[QBLK * KVBLK];  // 8 KB swizzled
  __shared__ float pmaxT[QBLK][12];
  __shared__ float psumT[QBLK][12];

  // ---- stage Q: fp32 -> bf16 LDS, 16B-slot XOR swizzle (slot ^ (row&7)) ----
  {
    const int row = tid >> 4;          // 0..31
    const int s0  = tid & 15;
    const float* qrow = Qf + boff + (size_t)(q0 + row) * DIM;
#pragma unroll
    for (int k = 0; k < 8; ++k) {
      const int slot2 = s0 + 16 * k;   // 128 slots of 8 bf16
      f32x4 a = *(const f32x4*)(qrow + slot2 * 8);
      f32x4 b = *(const f32x4*)(qrow + slot2 * 8 + 4);
      u16x8 pk;
#pragma unroll
      for (int j = 0; j < 4; ++j) { pk[j] = f2bf(a[j]); pk[4 + j] = f2bf(b[j]); }
      *(u16x8*)(Qs + row * 1024 + (slot2 ^ (row & 7)) * 8) = pk;
    }
  }

  const f32x4 zero4 = {0.f, 0.f, 0.f, 0.f};
  f32x4 o_acc[8][2];
#pragma unroll
  for (int mt = 0; mt < 8; ++mt)
#pragma unroll
    for (int nt = 0; nt < 2; ++nt) o_acc[mt][nt] = zero4;

  float m_reg[2] = {-1e30f, -1e30f};
  float l_reg[2] = {0.f, 0.f};

  const int ntiles = (kvhi - kvlo + KVBLK - 1) >> 7;
  // per-lane K base: panel (kv0>>4)+wv, unit row i16 -> +i16*8
  const unsigned short* kb = Kp + boff + (size_t)wv * KPAN + i16 * 8;
  // per-lane V base: d-row (wv*128 + i16), kv g*8
  const unsigned short* vb = Vp + boff + (size_t)(wv * 128 + i16) * 32 + g * 8;

  __syncthreads();   // Q visible

  for (int t = 0; t < ntiles; ++t) {
    const int kv0 = kvlo + t * KVBLK;
    const unsigned short* kt = kb + (size_t)(kv0 >> 4) * KPAN;  // this strip's panel
    const size_t vt0 = (size_t)(kv0 >> 5) * PAN;                // V panel base

    f32x4 sacc[2];
    sacc[0] = zero4; sacc[1] = zero4;
    bf16x8 vV0[8], vV1[8], vV2[8], vV3[8];

    // ---- QK^T: 8 phases, K frags direct global->reg (coalesced) ----
#pragma unroll
    for (int c = 0; c < 8; ++c) {
      if (c == 0) {   // issue V frags kc0,kc1 early (hide under QK)
#pragma unroll
        for (int mt = 0; mt < 8; ++mt) {
          vV0[mt] = __builtin_bit_cast(bf16x8,
              *(const u16x8*)(vb + vt0 + (size_t)mt * 512));
          vV1[mt] = __builtin_bit_cast(bf16x8,
              *(const u16x8*)(vb + vt0 + PAN + (size_t)mt * 512));
        }
      }
      const unsigned short* qrb0 = Qs + (0 * 16 + i16) * 1024;
      const unsigned short* qrb1 = Qs + (1 * 16 + i16) * 1024;
      bf16x8 kf[4], qf0[4], qf1[4];
#pragma unroll
      for (int kk = 0; kk < 4; ++kk) {
        kf[kk]  = __builtin_bit_cast(bf16x8,
            *(const u16x8*)(kt + (size_t)(c * 16 + kk * 4 + g) * 128));
        qf0[kk] = __builtin_bit_cast(bf16x8, *(const u16x8*)(qrb0 + ((c * 16 + kk * 4 + g) ^ swz) * 8));
        qf1[kk] = __builtin_bit_cast(bf16x8, *(const u16x8*)(qrb1 + ((c * 16 + kk * 4 + g) ^ swz) * 8));
      }
      __builtin_amdgcn_s_setprio(1);
#pragma unroll
      for (int kk = 0; kk < 4; ++kk) {
        sacc[0] = __builtin_amdgcn_mfma_f32_16x16x32_bf16(kf[kk], qf0[kk], sacc[0], 0, 0, 0);
        sacc[1] = __builtin_amdgcn_mfma_f32_16x16x32_bf16(kf[kk], qf1[kk], sacc[1], 0, 0, 0);
      }
      __builtin_amdgcn_s_setprio(0);
    }

    // ---- softmax: mask+scale, strip reduce, cross-wave combine ----
    float pm[2];
#pragma unroll
    for (int nt = 0; nt < 2; ++nt) {
      const int qg = q0 + nt * 16 + i16;
      const int kvbase = kv0 + wv * 16 + g * 4;
#pragma unroll
      for (int j = 0; j < 4; ++j) {
        const bool valid = (kvbase + j) <= qg;
        sacc[nt][j] = valid ? sacc[nt][j] * 0.03125f : -1e30f;
      }
      float v = fmaxf(fmaxf(sacc[nt][0], sacc[nt][1]), fmaxf(sacc[nt][2], sacc[nt][3]));
      v = fmaxf(v, __shfl_xor(v, 16));
      v = fmaxf(v, __shfl_xor(v, 32));
      pm[nt] = v;
    }
    if (lane < 32) pmaxT[(lane >> 4) * 16 + (lane & 15)][wv] = (lane < 16) ? pm[0] : pm[1];
    __syncthreads();   // A: pmax partials visible

    float alpha[2];
#pragma unroll
    for (int nt = 0; nt < 2; ++nt) {
      const float* pr = &pmaxT[nt * 16 + i16][0];
      f32x4 a = *(const f32x4*)(pr);
      f32x4 b = *(const f32x4*)(pr + 4);
      float mx = fmaxf(fmaxf(fmaxf(a[0], a[1]), fmaxf(a[2], a[3])),
                       fmaxf(fmaxf(b[0], b[1]), fmaxf(b[2], b[3])));
      const float m_new = fmaxf(m_reg[nt], mx);
      alpha[nt] = __expf(m_reg[nt] - m_new);
      m_reg[nt] = m_new;

      float ps = 0.f;
      u16x4 pw;
#pragma unroll
      for (int j = 0; j < 4; ++j) {
        const float p = __expf(sacc[nt][j] - m_new);   // masked -> 0
        ps += p;
        pw[j] = f2bf(p);
      }
      const int pslot = (wv * 2 + (g >> 1)) ^ swz;
      *(u16x4*)(Pl + (nt * 16 + i16) * 128 + pslot * 8 + (g & 1) * 4) = pw;
      ps += __shfl_xor(ps, 16);
      ps += __shfl_xor(ps, 32);
      pm[nt] = ps;
    }
    if (lane < 32) psumT[(lane >> 4) * 16 + (lane & 15)][wv] = (lane < 16) ? pm[0] : pm[1];
    __syncthreads();   // B: P + psum visible

    // ---- l update + O rescale ----
#pragma unroll
    for (int nt = 0; nt < 2; ++nt) {
      const float* pr = &psumT[nt * 16 + i16][0];
      f32x4 a = *(const f32x4*)(pr);
      f32x4 b = *(const f32x4*)(pr + 4);
      const float st = (a[0] + a[1] + a[2] + a[3]) + (b[0] + b[1] + b[2] + b[3]);
      l_reg[nt] = alpha[nt] * l_reg[nt] + st;
#pragma unroll
      for (int mt = 0; mt < 8; ++mt)
#pragma unroll
        for (int j = 0; j < 4; ++j) o_acc[mt][nt][j] *= alpha[nt];
    }

#define PV_STEP(KC, VREG)                                                      \
    do {                                                                        \
      bf16x8 pfa = __builtin_bit_cast(bf16x8, *(const u16x8*)(                  \
          Pl + (0 * 16 + i16) * 128 + (((KC) * 4 + g) ^ swz) * 8));             \
      bf16x8 pfb = __builtin_bit_cast(bf16x8, *(const u16x8*)(                  \
          Pl + (1 * 16 + i16) * 128 + (((KC) * 4 + g) ^ swz) * 8));             \
      __builtin_amdgcn_s_setprio(1);                                            \
      _Pragma("unroll")                                                         \
      for (int mt = 0; mt < 8; ++mt) {                                          \
        o_acc[mt][0] = __builtin_amdgcn_mfma_f32_16x16x32_bf16(VREG[mt], pfa,   \
                                                               o_acc[mt][0], 0, 0, 0); \
        o_acc[mt][1] = __builtin_amdgcn_mfma_f32_16x16x32_bf16(VREG[mt], pfb,   \
                                                               o_acc[mt][1], 0, 0, 0); \
      }                                                                         \
      __builtin_amdgcn_s_setprio(0);                                            \
    } while (0)

#pragma unroll
    for (int mt = 0; mt < 8; ++mt)   // prefetch kc2 (panel +2)
      vV2[mt] = __builtin_bit_cast(bf16x8,
          *(const u16x8*)(vb + vt0 + 2 * PAN + (size_t)mt * 512));
    PV_STEP(0, vV0);
#pragma unroll
    for (int mt = 0; mt < 8; ++mt)   // prefetch kc3 (panel +3)
      vV3[mt] = __builtin_bit_cast(bf16x8,
          *(const u16x8*)(vb + vt0 + 3 * PAN + (size_t)mt * 512));
    PV_STEP(1, vV1);
    PV_STEP(2, vV2);
    PV_STEP(3, vV3);
#undef PV_STEP

    __syncthreads();   // C: P consumed before next tile overwrites
  }

  // ---- epilogue ----
  if (slot < 0) {
#pragma unroll
    for (int nt = 0; nt < 2; ++nt) {
      const float linv = 1.f / l_reg[nt];
      const size_t qoff = boff + (size_t)(q0 + nt * 16 + i16) * DIM + wv * 128 + g * 4;
#pragma unroll
      for (int mt = 0; mt < 8; ++mt) {
        f32x4 o;
#pragma unroll
        for (int j = 0; j < 4; ++j) o[j] = o_acc[mt][nt][j] * linv;
        *(f32x4*)(Out + qoff + mt * 16) = o;
      }
    }
  } else {
    const size_t pbase = (size_t)slot * (QBLK * DIM);
#pragma unroll
    for (int nt = 0; nt < 2; ++nt) {
      const size_t qoff = pbase + (size_t)(nt * 16 + i16) * DIM + wv * 128 + g * 4;
#pragma unroll
      for (int mt = 0; mt < 8; ++mt)
        *(f32x4*)(Opart + qoff + mt * 16) = o_acc[mt][nt];
    }
    if (wv == 0 && lane < 16) {
#pragma unroll
      for (int nt = 0; nt < 2; ++nt) {
        Ml[(size_t)slot * 64 + (nt * 16 + lane) * 2 + 0] = m_reg[nt];
        Ml[(size_t)slot * 64 + (nt * 16 + lane) * 2 + 1] = l_reg[nt];
      }
    }
  }
}

// Deterministic flash-merge of <=4 partials per (batch, qtile).
__global__ void combine_kernel(const float* __restrict__ Opart,
                               const float* __restrict__ Ml,
                               float* __restrict__ Out, int mode) {
  const int NT  = (mode == 2) ? 48 : 32;
  const int qt0 = (mode == 2) ? 16 : 32;
  const int b   = blockIdx.x / NT;
  const int qt  = qt0 + blockIdx.x % NT;
  const int n   = (mode == 2) ? ((qt >> 4) + 1) : 2;

  int slots[4];
  if (mode == 2) {
    slots[0] = b * 144 + (qt - 16);
    slots[1] = b * 144 + 48 + (qt - 16);
    slots[2] = b * 144 + 96 + (qt - 32);
    slots[3] = b * 144 + 128 + (qt - 48);
  } else {
    slots[0] = b * 64 + (qt - 32);
    slots[1] = b * 64 + 32 + (qt - 32);
    slots[2] = slots[3] = 0;
  }

  __shared__ float wsh[4][32];
  __shared__ float lsh[32];
  const int t = threadIdx.x;   // 256
  if (t < 32) {
    float mc[4], lc[4];
    float m = -1e30f;
    for (int c = 0; c < n; ++c) {
      mc[c] = Ml[(size_t)slots[c] * 64 + t * 2 + 0];
      lc[c] = Ml[(size_t)slots[c] * 64 + t * 2 + 1];
      m = fmaxf(m, mc[c]);
    }
    float l = 0.f;
    for (int c = 0; c < n; ++c) {
      const float w = __expf(mc[c] - m);
      wsh[c][t] = w;
      l += w * lc[c];
    }
    lsh[t] = 1.f / l;
  }
  __syncthreads();

  const size_t obase = ((size_t)b * SEQ + (size_t)qt * 32) * DIM;
  const int d = t * 4;
  for (int q = 0; q < 32; ++q) {
    f32x4 acc = {0.f, 0.f, 0.f, 0.f};
    for (int c = 0; c < n; ++c) {
      f32x4 x = *(const f32x4*)(Opart + (size_t)slots[c] * (QBLK * DIM) + (size_t)q * DIM + d);
      const float w = wsh[c][q];
#pragma unroll
      for (int j = 0; j < 4; ++j) acc[j] += w * x[j];
    }
    const float li = lsh[q];
    f32x4 o;
#pragma unroll
    for (int j = 0; j < 4; ++j) o[j] = acc[j] * li;
    *(f32x4*)(Out + obase + (size_t)q * DIM + d) = o;
  }
}

// Emergency fallback - correct, not fast.
__global__ void attn_naive(const float* __restrict__ Q, const float* __restrict__ K,
                           const float* __restrict__ V, float* __restrict__ Out) {
  const int b = blockIdx.y, q = blockIdx.x;
  const int t = threadIdx.x;
  __shared__ float qs[DIM];
  __shared__ float sc[SEQ];
  __shared__ float red[2];
  const size_t boff = (size_t)b * SEQ * DIM;
  for (int d = t; d < DIM; d += 256) qs[d] = Q[boff + (size_t)q * DIM + d];
  __syncthreads();
  const int kvmax = q + 1;
  for (int kv = t; kv < kvmax; kv += 256) {
    const float* kr = K + boff + (size_t)kv * DIM;
    float s = 0.f;
    for (int d = 0; d < DIM; ++d) s += qs[d] * kr[d];
    sc[kv] = s * 0.03125f;
  }
  __syncthreads();
  if (t == 0) {
    float m = -1e30f;
    for (int kv = 0; kv < kvmax; ++kv) m = fmaxf(m, sc[kv]);
    red[0] = m;
  }
  __syncthreads();
  const float m = red[0];
  for (int kv = t; kv < kvmax; kv += 256) sc[kv] = __expf(sc[kv] - m);
  __syncthreads();
  if (t == 0) {
    float l = 0.f;
    for (int kv = 0; kv < kvmax; ++kv) l += sc[kv];
    red[1] = l;
  }
  __syncthreads();
  const float linv = 1.f / red[1];
  for (int d = t; d < DIM; d += 256) {
    float o = 0.f;
    for (int kv = 0; kv < kvmax; ++kv) o += sc[kv] * V[boff + (size_t)kv * DIM + d];
    Out[boff + (size_t)q * DIM + d] = o * linv;
  }
}

extern "C" void kernel_launch(void* const* d_in, const int* in_sizes, int n_in,
                              void* d_out, int out_size, void* d_ws, size_t ws_size,
                              hipStream_t stream) {
  (void)in_sizes; (void)n_in; (void)out_size;
  const float* Q = (const float*)d_in[0];
  const float* K = (const float*)d_in[1];
  const float* V = (const float*)d_in[2];
  float* Out = (float*)d_out;

  const size_t nelem   = (size_t)B_SZ * SEQ * DIM;            // 8.4M / tensor
  const size_t bf_b    = nelem * sizeof(unsigned short);      // 16 MB
  const size_t ml_b    = (size_t)640 * 64 * sizeof(float);    // 160 KB (max)
  const size_t part1_b = (size_t)256 * QBLK * DIM * sizeof(float);   // 32 MB
  const size_t part2_b = (size_t)576 * QBLK * DIM * sizeof(float);   // 72 MB

  const size_t need0 = 2 * bf_b;
  const size_t need1 = 2 * bf_b + ml_b + part1_b;
  const size_t need2 = 2 * bf_b + ml_b + part2_b;

  const int mode = (ws_size >= need2) ? 2 : (ws_size >= need1) ? 1
                   : (ws_size >= need0) ? 0 : -1;

  if (mode < 0) {
    hipLaunchKernelGGL(attn_naive, dim3(SEQ, B_SZ), dim3(256), 0, stream, Q, K, V, Out);
    return;
  }

  unsigned short* Kp = (unsigned short*)d_ws;
  unsigned short* Vp = Kp + nelem;
  float* Ml    = (float*)(Vp + nelem);
  float* Opart = Ml + 640 * 64;

  hipLaunchKernelGGL(transpose_k_kernel, dim3(DIM / 128, SEQ / 16, B_SZ), dim3(256),
                     0, stream, K, Kp);
  hipLaunchKernelGGL(transpose_v_kernel, dim3(DIM / 32, SEQ / 32, B_SZ), dim3(256),
                     0, stream, V, Vp);

  const int grid = (mode == 2) ? 640 : (mode == 1) ? 384 : 256;
  hipLaunchKernelGGL(attn_part, dim3(grid), dim3(NWAVES * 64), 0, stream,
                     Q, Kp, Vp, Out, Opart, Ml, mode);

  if (mode >= 1) {
    const int cgrid = (mode == 2) ? (B_SZ * 48) : (B_SZ * 32);
    hipLaunchKernelGGL(combine_kernel, dim3(cgrid), dim3(256), 0, stream,
                       Opart, Ml, Out, mode);
  }
}

// Round 11
// 414.427 us; speedup vs baseline: 1.0528x; 1.0528x over previous
//
#include <hip/hip_runtime.h>
#include <stdint.h>

// Causal attention, B=4, SQ=SK=2048, D=1024, fp32 in/out, bf16 MFMA compute.
// R10 = R9 with K ALSO panel-transformed -> direct global->VGPR (coalesced),
//      glds/Kc deleted. LDS 75KB -> 2 blocks/CU (16 waves/CU). Same kv-split
//      + combine + swapped-QK^T + register softmax as R7/R9.
// Layouts: Kp[b][kv/16][d/8][kv%16][8d]  (A-frag load = 1KB/wave contiguous)
//          Vp[b][sk/32][d][sk%32]        (PV frag load = 1KB/wave contiguous)

#define B_SZ 4
#define SEQ 2048
#define DIM 1024
#define QBLK 32
#define KVBLK 128
#define NWAVES 8
#define PAN  ((size_t)DIM * 32)   // elems per 32-kv V panel
#define KPAN ((size_t)DIM * 16)   // elems per 16-kv K panel

typedef __bf16 bf16x8 __attribute__((ext_vector_type(8)));
typedef unsigned short u16x8 __attribute__((ext_vector_type(8)));
typedef unsigned short u16x4 __attribute__((ext_vector_type(4)));
typedef float f32x4 __attribute__((ext_vector_type(4)));

__device__ __forceinline__ unsigned short f2bf(float f) {
  union { float f; uint32_t u; } c; c.f = f;
  uint32_t u = c.u;
  u += 0x7FFFu + ((u >> 16) & 1u);   // RNE
  return (unsigned short)(u >> 16);
}

// K[b][kv][d] fp32 -> Kp[b][kv/16][d/8][kv%16][8] bf16
__global__ void transpose_k_kernel(const float* __restrict__ in,
                                   unsigned short* __restrict__ out) {
  const int b   = blockIdx.z;
  const int kv0 = blockIdx.y * 16;
  const int d0  = blockIdx.x * 128;
  const int t   = threadIdx.x;          // 256
  const int kvl = t >> 4;               // 0..15
  const int uu  = t & 15;               // 0..15 d-units
  const int d   = d0 + uu * 8;
  const float* src = in + (size_t)b * SEQ * DIM + (size_t)(kv0 + kvl) * DIM + d;
  f32x4 a = *(const f32x4*)(src);
  f32x4 c = *(const f32x4*)(src + 4);
  u16x8 pk;
#pragma unroll
  for (int j = 0; j < 4; ++j) { pk[j] = f2bf(a[j]); pk[4 + j] = f2bf(c[j]); }
  *(u16x8*)(out + (size_t)b * SEQ * DIM + (size_t)blockIdx.y * KPAN
            + (size_t)(d >> 3) * 128 + kvl * 8) = pk;
}

// V[b][sk][d] fp32 -> Vp[b][sk/32][d][sk%32] bf16 (panel-transposed)
__global__ void transpose_v_kernel(const float* __restrict__ in,
                                   unsigned short* __restrict__ out) {
  __shared__ unsigned short tile[32][33];
  const int b  = blockIdx.z;
  const int s0 = blockIdx.y * 32;
  const int d0 = blockIdx.x * 32;
  const int t  = threadIdx.x;
  const int r  = t >> 3;
  const int c4 = (t & 7) * 4;
  const size_t ibase = (size_t)b * SEQ * DIM;
  const size_t obase = (size_t)b * DIM * SEQ;

  f32x4 v = *(const f32x4*)(in + ibase + (size_t)(s0 + r) * DIM + d0 + c4);
#pragma unroll
  for (int j = 0; j < 4; ++j) tile[r][c4 + j] = f2bf(v[j]);
  __syncthreads();
  u16x4 o;
#pragma unroll
  for (int j = 0; j < 4; ++j) o[j] = tile[c4 + j][r];
  *(u16x4*)(out + obase + (size_t)(s0 >> 5) * PAN + (size_t)(d0 + r) * 32 + c4) = o;
}

__device__ __forceinline__ int imin(int a, int b) { return a < b ? a : b; }

__global__ __launch_bounds__(512, 4) void attn_part(
    const float* __restrict__ Qf, const unsigned short* __restrict__ Kp,
    const unsigned short* __restrict__ Vp, float* __restrict__ Out,
    float* __restrict__ Opart, float* __restrict__ Ml, int mode) {
  const int tid  = threadIdx.x;
  const int lane = tid & 63;
  const int wv   = tid >> 6;        // 0..7: kv strip (QK) and 128-wide D slice (PV)
  const int g    = lane >> 4;       // 0..3
  const int i16  = lane & 15;
  const int swz  = i16 & 7;

  // ---- work-item decode: chunk-major, XCD-affine, heavy-first ----
  const int IPX = (mode == 2) ? 80 : (mode == 1) ? 48 : 32;
  const int IPB = (mode == 2) ? 160 : (mode == 1) ? 96 : 64;
  const int item  = (blockIdx.x & 7) * IPX + (blockIdx.x >> 3);
  const int batch = item / IPB;
  const int r     = IPB - 1 - (item % IPB);

  int qt, kvlo, kvhi, slot;
  if (mode == 2) {
    if (r < 16)       { qt = r;             kvlo = 0;    kvhi = 32 * qt + 32;             slot = -1; }
    else if (r < 64)  { qt = r;             kvlo = 0;    kvhi = 512;                      slot = batch * 144 + (r - 16); }
    else if (r < 112) { qt = 16 + (r - 64); kvlo = 512;  kvhi = imin(1024, 32 * qt + 32); slot = batch * 144 + (r - 16); }
    else if (r < 144) { qt = 32 + (r - 112); kvlo = 1024; kvhi = imin(1536, 32 * qt + 32); slot = batch * 144 + (r - 16); }
    else              { qt = 48 + (r - 144); kvlo = 1536; kvhi = 32 * qt + 32;            slot = batch * 144 + (r - 16); }
  } else if (mode == 1) {
    if (r < 32)       { qt = r;             kvlo = 0;    kvhi = 32 * qt + 32;  slot = -1; }
    else if (r < 64)  { qt = 32 + (r - 32); kvlo = 0;    kvhi = 1024;          slot = batch * 64 + (r - 32); }
    else              { qt = 32 + (r - 64); kvlo = 1024; kvhi = 32 * qt + 32;  slot = batch * 64 + (r - 32); }
  } else {
    qt = r; kvlo = 0; kvhi = 32 * qt + 32; slot = -1;
  }

  const int q0 = qt * QBLK;
  const size_t boff = (size_t)batch * SEQ * DIM;

  __shared__ __align__(16) unsigned short Qs[QBLK * 1024];   // 64 KB swizzled
  __shared__ __align__(16) unsigned short Pl[QBLK * KVBLK];  // 8 KB swizzled
  __shared__ float pmaxT[QBLK][12];
  __shared__ float psumT[QBLK][12];

  // ---- stage Q: fp32 -> bf16 LDS, 16B-slot XOR swizzle (slot ^ (row&7)) ----
  {
    const int row = tid >> 4;          // 0..31
    const int s0  = tid & 15;
    const float* qrow = Qf + boff + (size_t)(q0 + row) * DIM;
#pragma unroll
    for (int k = 0; k < 8; ++k) {
      const int slot2 = s0 + 16 * k;   // 128 slots of 8 bf16
      f32x4 a = *(const f32x4*)(qrow + slot2 * 8);
      f32x4 b = *(const f32x4*)(qrow + slot2 * 8 + 4);
      u16x8 pk;
#pragma unroll
      for (int j = 0; j < 4; ++j) { pk[j] = f2bf(a[j]); pk[4 + j] = f2bf(b[j]); }
      *(u16x8*)(Qs + row * 1024 + (slot2 ^ (row & 7)) * 8) = pk;
    }
  }

  const f32x4 zero4 = {0.f, 0.f, 0.f, 0.f};
  f32x4 o_acc[8][2];
#pragma unroll
  for (int mt = 0; mt < 8; ++mt)
#pragma unroll
    for (int nt = 0; nt < 2; ++nt) o_acc[mt][nt] = zero4;

  float m_reg[2] = {-1e30f, -1e30f};
  float l_reg[2] = {0.f, 0.f};

  const int ntiles = (kvhi - kvlo + KVBLK - 1) >> 7;
  // per-lane K base: panel (kv0>>4)+wv, unit row i16 -> +i16*8
  const unsigned short* kb = Kp + boff + (size_t)wv * KPAN + i16 * 8;
  // per-lane V base: d-row (wv*128 + i16), kv g*8
  const unsigned short* vb = Vp + boff + (size_t)(wv * 128 + i16) * 32 + g * 8;

  __syncthreads();   // Q visible

  for (int t = 0; t < ntiles; ++t) {
    const int kv0 = kvlo + t * KVBLK;
    const unsigned short* kt = kb + (size_t)(kv0 >> 4) * KPAN;  // this strip's panel
    const size_t vt0 = (size_t)(kv0 >> 5) * PAN;                // V panel base

    f32x4 sacc[2];
    sacc[0] = zero4; sacc[1] = zero4;
    bf16x8 vV0[8], vV1[8], vV2[8], vV3[8];

    // ---- QK^T: 8 phases, K frags direct global->reg (coalesced) ----
#pragma unroll
    for (int c = 0; c < 8; ++c) {
      if (c == 0) {   // issue V frags kc0,kc1 early (hide under QK)
#pragma unroll
        for (int mt = 0; mt < 8; ++mt) {
          vV0[mt] = __builtin_bit_cast(bf16x8,
              *(const u16x8*)(vb + vt0 + (size_t)mt * 512));
          vV1[mt] = __builtin_bit_cast(bf16x8,
              *(const u16x8*)(vb + vt0 + PAN + (size_t)mt * 512));
        }
      }
      const unsigned short* qrb0 = Qs + (0 * 16 + i16) * 1024;
      const unsigned short* qrb1 = Qs + (1 * 16 + i16) * 1024;
      bf16x8 kf[4], qf0[4], qf1[4];
#pragma unroll
      for (int kk = 0; kk < 4; ++kk) {
        kf[kk]  = __builtin_bit_cast(bf16x8,
            *(const u16x8*)(kt + (size_t)(c * 16 + kk * 4 + g) * 128));
        qf0[kk] = __builtin_bit_cast(bf16x8, *(const u16x8*)(qrb0 + ((c * 16 + kk * 4 + g) ^ swz) * 8));
        qf1[kk] = __builtin_bit_cast(bf16x8, *(const u16x8*)(qrb1 + ((c * 16 + kk * 4 + g) ^ swz) * 8));
      }
      __builtin_amdgcn_s_setprio(1);
#pragma unroll
      for (int kk = 0; kk < 4; ++kk) {
        sacc[0] = __builtin_amdgcn_mfma_f32_16x16x32_bf16(kf[kk], qf0[kk], sacc[0], 0, 0, 0);
        sacc[1] = __builtin_amdgcn_mfma_f32_16x16x32_bf16(kf[kk], qf1[kk], sacc[1], 0, 0, 0);
      }
      __builtin_amdgcn_s_setprio(0);
    }

    // ---- softmax: mask+scale, strip reduce, cross-wave combine ----
    float pm[2];
#pragma unroll
    for (int nt = 0; nt < 2; ++nt) {
      const int qg = q0 + nt * 16 + i16;
      const int kvbase = kv0 + wv * 16 + g * 4;
#pragma unroll
      for (int j = 0; j < 4; ++j) {
        const bool valid = (kvbase + j) <= qg;
        sacc[nt][j] = valid ? sacc[nt][j] * 0.03125f : -1e30f;
      }
      float v = fmaxf(fmaxf(sacc[nt][0], sacc[nt][1]), fmaxf(sacc[nt][2], sacc[nt][3]));
      v = fmaxf(v, __shfl_xor(v, 16));
      v = fmaxf(v, __shfl_xor(v, 32));
      pm[nt] = v;
    }
    if (lane < 32) pmaxT[(lane >> 4) * 16 + (lane & 15)][wv] = (lane < 16) ? pm[0] : pm[1];
    __syncthreads();   // A: pmax partials visible

    float alpha[2];
#pragma unroll
    for (int nt = 0; nt < 2; ++nt) {
      const float* pr = &pmaxT[nt * 16 + i16][0];
      f32x4 a = *(const f32x4*)(pr);
      f32x4 b = *(const f32x4*)(pr + 4);
      float mx = fmaxf(fmaxf(fmaxf(a[0], a[1]), fmaxf(a[2], a[3])),
                       fmaxf(fmaxf(b[0], b[1]), fmaxf(b[2], b[3])));
      const float m_new = fmaxf(m_reg[nt], mx);
      alpha[nt] = __expf(m_reg[nt] - m_new);
      m_reg[nt] = m_new;

      float ps = 0.f;
      u16x4 pw;
#pragma unroll
      for (int j = 0; j < 4; ++j) {
        const float p = __expf(sacc[nt][j] - m_new);   // masked -> 0
        ps += p;
        pw[j] = f2bf(p);
      }
      const int pslot = (wv * 2 + (g >> 1)) ^ swz;
      *(u16x4*)(Pl + (nt * 16 + i16) * 128 + pslot * 8 + (g & 1) * 4) = pw;
      ps += __shfl_xor(ps, 16);
      ps += __shfl_xor(ps, 32);
      pm[nt] = ps;
    }
    if (lane < 32) psumT[(lane >> 4) * 16 + (lane & 15)][wv] = (lane < 16) ? pm[0] : pm[1];
    __syncthreads();   // B: P + psum visible

    // ---- l update + O rescale ----
#pragma unroll
    for (int nt = 0; nt < 2; ++nt) {
      const float* pr = &psumT[nt * 16 + i16][0];
      f32x4 a = *(const f32x4*)(pr);
      f32x4 b = *(const f32x4*)(pr + 4);
      const float st = (a[0] + a[1] + a[2] + a[3]) + (b[0] + b[1] + b[2] + b[3]);
      l_reg[nt] = alpha[nt] * l_reg[nt] + st;
#pragma unroll
      for (int mt = 0; mt < 8; ++mt)
#pragma unroll
        for (int j = 0; j < 4; ++j) o_acc[mt][nt][j] *= alpha[nt];
    }

#define PV_STEP(KC, VREG)                                                      \
    do {                                                                        \
      bf16x8 pfa = __builtin_bit_cast(bf16x8, *(const u16x8*)(                  \
          Pl + (0 * 16 + i16) * 128 + (((KC) * 4 + g) ^ swz) * 8));             \
      bf16x8 pfb = __builtin_bit_cast(bf16x8, *(const u16x8*)(                  \
          Pl + (1 * 16 + i16) * 128 + (((KC) * 4 + g) ^ swz) * 8));             \
      __builtin_amdgcn_s_setprio(1);                                            \
      _Pragma("unroll")                                                         \
      for (int mt = 0; mt < 8; ++mt) {                                          \
        o_acc[mt][0] = __builtin_amdgcn_mfma_f32_16x16x32_bf16(VREG[mt], pfa,   \
                                                               o_acc[mt][0], 0, 0, 0); \
        o_acc[mt][1] = __builtin_amdgcn_mfma_f32_16x16x32_bf16(VREG[mt], pfb,   \
                                                               o_acc[mt][1], 0, 0, 0); \
      }                                                                         \
      __builtin_amdgcn_s_setprio(0);                                            \
    } while (0)

#pragma unroll
    for (int mt = 0; mt < 8; ++mt)   // prefetch kc2 (panel +2)
      vV2[mt] = __builtin_bit_cast(bf16x8,
          *(const u16x8*)(vb + vt0 + 2 * PAN + (size_t)mt * 512));
    PV_STEP(0, vV0);
#pragma unroll
    for (int mt = 0; mt < 8; ++mt)   // prefetch kc3 (panel +3)
      vV3[mt] = __builtin_bit_cast(bf16x8,
          *(const u16x8*)(vb + vt0 + 3 * PAN + (size_t)mt * 512));
    PV_STEP(1, vV1);
    PV_STEP(2, vV2);
    PV_STEP(3, vV3);
#undef PV_STEP

    __syncthreads();   // C: P consumed before next tile overwrites
  }

  // ---- epilogue ----
  if (slot < 0) {
#pragma unroll
    for (int nt = 0; nt < 2; ++nt) {
      const float linv = 1.f / l_reg[nt];
      const size_t qoff = boff + (size_t)(q0 + nt * 16 + i16) * DIM + wv * 128 + g * 4;
#pragma unroll
      for (int mt = 0; mt < 8; ++mt) {
        f32x4 o;
#pragma unroll
        for (int j = 0; j < 4; ++j) o[j] = o_acc[mt][nt][j] * linv;
        *(f32x4*)(Out + qoff + mt * 16) = o;
      }
    }
  } else {
    const size_t pbase = (size_t)slot * (QBLK * DIM);
#pragma unroll
    for (int nt = 0; nt < 2; ++nt) {
      const size_t qoff = pbase + (size_t)(nt * 16 + i16) * DIM + wv * 128 + g * 4;
#pragma unroll
      for (int mt = 0; mt < 8; ++mt)
        *(f32x4*)(Opart + qoff + mt * 16) = o_acc[mt][nt];
    }
    if (wv == 0 && lane < 16) {
#pragma unroll
      for (int nt = 0; nt < 2; ++nt) {
        Ml[(size_t)slot * 64 + (nt * 16 + lane) * 2 + 0] = m_reg[nt];
        Ml[(size_t)slot * 64 + (nt * 16 + lane) * 2 + 1] = l_reg[nt];
      }
    }
  }
}

// Deterministic flash-merge of <=4 partials per (batch, qtile).
__global__ void combine_kernel(const float* __restrict__ Opart,
                               const float* __restrict__ Ml,
                               float* __restrict__ Out, int mode) {
  const int NT  = (mode == 2) ? 48 : 32;
  const int qt0 = (mode == 2) ? 16 : 32;
  const int b   = blockIdx.x / NT;
  const int qt  = qt0 + blockIdx.x % NT;
  const int n   = (mode == 2) ? ((qt >> 4) + 1) : 2;

  int slots[4];
  if (mode == 2) {
    slots[0] = b * 144 + (qt - 16);
    slots[1] = b * 144 + 48 + (qt - 16);
    slots[2] = b * 144 + 96 + (qt - 32);
    slots[3] = b * 144 + 128 + (qt - 48);
  } else {
    slots[0] = b * 64 + (qt - 32);
    slots[1] = b * 64 + 32 + (qt - 32);
    slots[2] = slots[3] = 0;
  }

  __shared__ float wsh[4][32];
  __shared__ float lsh[32];
  const int t = threadIdx.x;   // 256
  if (t < 32) {
    float mc[4], lc[4];
    float m = -1e30f;
    for (int c = 0; c < n; ++c) {
      mc[c] = Ml[(size_t)slots[c] * 64 + t * 2 + 0];
      lc[c] = Ml[(size_t)slots[c] * 64 + t * 2 + 1];
      m = fmaxf(m, mc[c]);
    }
    float l = 0.f;
    for (int c = 0; c < n; ++c) {
      const float w = __expf(mc[c] - m);
      wsh[c][t] = w;
      l += w * lc[c];
    }
    lsh[t] = 1.f / l;
  }
  __syncthreads();

  const size_t obase = ((size_t)b * SEQ + (size_t)qt * 32) * DIM;
  const int d = t * 4;
  for (int q = 0; q < 32; ++q) {
    f32x4 acc = {0.f, 0.f, 0.f, 0.f};
    for (int c = 0; c < n; ++c) {
      f32x4 x = *(const f32x4*)(Opart + (size_t)slots[c] * (QBLK * DIM) + (size_t)q * DIM + d);
      const float w = wsh[c][q];
#pragma unroll
      for (int j = 0; j < 4; ++j) acc[j] += w * x[j];
    }
    const float li = lsh[q];
    f32x4 o;
#pragma unroll
    for (int j = 0; j < 4; ++j) o[j] = acc[j] * li;
    *(f32x4*)(Out + obase + (size_t)q * DIM + d) = o;
  }
}

// Emergency fallback - correct, not fast.
__global__ void attn_naive(const float* __restrict__ Q, const float* __restrict__ K,
                           const float* __restrict__ V, float* __restrict__ Out) {
  const int b = blockIdx.y, q = blockIdx.x;
  const int t = threadIdx.x;
  __shared__ float qs[DIM];
  __shared__ float sc[SEQ];
  __shared__ float red[2];
  const size_t boff = (size_t)b * SEQ * DIM;
  for (int d = t; d < DIM; d += 256) qs[d] = Q[boff + (size_t)q * DIM + d];
  __syncthreads();
  const int kvmax = q + 1;
  for (int kv = t; kv < kvmax; kv += 256) {
    const float* kr = K + boff + (size_t)kv * DIM;
    float s = 0.f;
    for (int d = 0; d < DIM; ++d) s += qs[d] * kr[d];
    sc[kv] = s * 0.03125f;
  }
  __syncthreads();
  if (t == 0) {
    float m = -1e30f;
    for (int kv = 0; kv < kvmax; ++kv) m = fmaxf(m, sc[kv]);
    red[0] = m;
  }
  __syncthreads();
  const float m = red[0];
  for (int kv = t; kv < kvmax; kv += 256) sc[kv] = __expf(sc[kv] - m);
  __syncthreads();
  if (t == 0) {
    float l = 0.f;
    for (int kv = 0; kv < kvmax; ++kv) l += sc[kv];
    red[1] = l;
  }
  __syncthreads();
  const float linv = 1.f / red[1];
  for (int d = t; d < DIM; d += 256) {
    float o = 0.f;
    for (int kv = 0; kv < kvmax; ++kv) o += sc[kv] * V[boff + (size_t)kv * DIM + d];
    Out[boff + (size_t)q * DIM + d] = o * linv;
  }
}

extern "C" void kernel_launch(void* const* d_in, const int* in_sizes, int n_in,
                              void* d_out, int out_size, void* d_ws, size_t ws_size,
                              hipStream_t stream) {
  (void)in_sizes; (void)n_in; (void)out_size;
  const float* Q = (const float*)d_in[0];
  const float* K = (const float*)d_in[1];
  const float* V = (const float*)d_in[2];
  float* Out = (float*)d_out;

  const size_t nelem   = (size_t)B_SZ * SEQ * DIM;            // 8.4M / tensor
  const size_t bf_b    = nelem * sizeof(unsigned short);      // 16 MB
  const size_t ml_b    = (size_t)640 * 64 * sizeof(float);    // 160 KB (max)
  const size_t part1_b = (size_t)256 * QBLK * DIM * sizeof(float);   // 32 MB
  const size_t part2_b = (size_t)576 * QBLK * DIM * sizeof(float);   // 72 MB

  const size_t need0 = 2 * bf_b;
  const size_t need1 = 2 * bf_b + ml_b + part1_b;
  const size_t need2 = 2 * bf_b + ml_b + part2_b;

  const int mode = (ws_size >= need2) ? 2 : (ws_size >= need1) ? 1
                   : (ws_size >= need0) ? 0 : -1;

  if (mode < 0) {
    hipLaunchKernelGGL(attn_naive, dim3(SEQ, B_SZ), dim3(256), 0, stream, Q, K, V, Out);
    return;
  }

  unsigned short* Kp = (unsigned short*)d_ws;
  unsigned short* Vp = Kp + nelem;
  float* Ml    = (float*)(Vp + nelem);
  float* Opart = Ml + 640 * 64;

  hipLaunchKernelGGL(transpose_k_kernel, dim3(DIM / 128, SEQ / 16, B_SZ), dim3(256),
                     0, stream, K, Kp);
  hipLaunchKernelGGL(transpose_v_kernel, dim3(DIM / 32, SEQ / 32, B_SZ), dim3(256),
                     0, stream, V, Vp);

  const int grid = (mode == 2) ? 640 : (mode == 1) ? 384 : 256;
  hipLaunchKernelGGL(attn_part, dim3(grid), dim3(NWAVES * 64), 0, stream,
                     Q, Kp, Vp, Out, Opart, Ml, mode);

  if (mode >= 1) {
    const int cgrid = (mode == 2) ? (B_SZ * 48) : (B_SZ * 32);
    hipLaunchKernelGGL(combine_kernel, dim3(cgrid), dim3(256), 0, stream,
                       Opart, Ml, Out, mode);
  }
}

// Round 12
// 152.051 us; speedup vs baseline: 2.8696x; 2.7256x over previous
//
#include <hip/hip_runtime.h>
#include <stdint.h>

// Causal attention, B=4, SQ=SK=2048, D=1024, fp32 in/out, bf16 MFMA compute.
// R11 = R10 (K panel-transformed -> direct global->VGPR coalesced, no glds/Kc,
//      LDS 75KB) with __launch_bounds__(512,2): R10's (512,4) forced a 64-VGPR
//      cap -> massive scratch spills (WRITE_SIZE 595MB). (512,2) restores the
//      128-VGPR budget (R9-proven, spill-free); HW can still fit 2 blocks/CU.
// Layouts: Kp[b][kv/16][d/8][kv%16][8d]  (A-frag load = 1KB/wave contiguous)
//          Vp[b][sk/32][d][sk%32]        (PV frag load = 1KB/wave contiguous)

#define B_SZ 4
#define SEQ 2048
#define DIM 1024
#define QBLK 32
#define KVBLK 128
#define NWAVES 8
#define PAN  ((size_t)DIM * 32)   // elems per 32-kv V panel
#define KPAN ((size_t)DIM * 16)   // elems per 16-kv K panel

typedef __bf16 bf16x8 __attribute__((ext_vector_type(8)));
typedef unsigned short u16x8 __attribute__((ext_vector_type(8)));
typedef unsigned short u16x4 __attribute__((ext_vector_type(4)));
typedef float f32x4 __attribute__((ext_vector_type(4)));

__device__ __forceinline__ unsigned short f2bf(float f) {
  union { float f; uint32_t u; } c; c.f = f;
  uint32_t u = c.u;
  u += 0x7FFFu + ((u >> 16) & 1u);   // RNE
  return (unsigned short)(u >> 16);
}

// K[b][kv][d] fp32 -> Kp[b][kv/16][d/8][kv%16][8] bf16
__global__ void transpose_k_kernel(const float* __restrict__ in,
                                   unsigned short* __restrict__ out) {
  const int b   = blockIdx.z;
  const int kv0 = blockIdx.y * 16;
  const int d0  = blockIdx.x * 128;
  const int t   = threadIdx.x;          // 256
  const int kvl = t >> 4;               // 0..15
  const int uu  = t & 15;               // 0..15 d-units
  const int d   = d0 + uu * 8;
  const float* src = in + (size_t)b * SEQ * DIM + (size_t)(kv0 + kvl) * DIM + d;
  f32x4 a = *(const f32x4*)(src);
  f32x4 c = *(const f32x4*)(src + 4);
  u16x8 pk;
#pragma unroll
  for (int j = 0; j < 4; ++j) { pk[j] = f2bf(a[j]); pk[4 + j] = f2bf(c[j]); }
  *(u16x8*)(out + (size_t)b * SEQ * DIM + (size_t)blockIdx.y * KPAN
            + (size_t)(d >> 3) * 128 + kvl * 8) = pk;
}

// V[b][sk][d] fp32 -> Vp[b][sk/32][d][sk%32] bf16 (panel-transposed)
__global__ void transpose_v_kernel(const float* __restrict__ in,
                                   unsigned short* __restrict__ out) {
  __shared__ unsigned short tile[32][33];
  const int b  = blockIdx.z;
  const int s0 = blockIdx.y * 32;
  const int d0 = blockIdx.x * 32;
  const int t  = threadIdx.x;
  const int r  = t >> 3;
  const int c4 = (t & 7) * 4;
  const size_t ibase = (size_t)b * SEQ * DIM;
  const size_t obase = (size_t)b * DIM * SEQ;

  f32x4 v = *(const f32x4*)(in + ibase + (size_t)(s0 + r) * DIM + d0 + c4);
#pragma unroll
  for (int j = 0; j < 4; ++j) tile[r][c4 + j] = f2bf(v[j]);
  __syncthreads();
  u16x4 o;
#pragma unroll
  for (int j = 0; j < 4; ++j) o[j] = tile[c4 + j][r];
  *(u16x4*)(out + obase + (size_t)(s0 >> 5) * PAN + (size_t)(d0 + r) * 32 + c4) = o;
}

__device__ __forceinline__ int imin(int a, int b) { return a < b ? a : b; }

__global__ __launch_bounds__(512, 2) void attn_part(
    const float* __restrict__ Qf, const unsigned short* __restrict__ Kp,
    const unsigned short* __restrict__ Vp, float* __restrict__ Out,
    float* __restrict__ Opart, float* __restrict__ Ml, int mode) {
  const int tid  = threadIdx.x;
  const int lane = tid & 63;
  const int wv   = tid >> 6;        // 0..7: kv strip (QK) and 128-wide D slice (PV)
  const int g    = lane >> 4;       // 0..3
  const int i16  = lane & 15;
  const int swz  = i16 & 7;

  // ---- work-item decode: chunk-major, XCD-affine, heavy-first ----
  const int IPX = (mode == 2) ? 80 : (mode == 1) ? 48 : 32;
  const int IPB = (mode == 2) ? 160 : (mode == 1) ? 96 : 64;
  const int item  = (blockIdx.x & 7) * IPX + (blockIdx.x >> 3);
  const int batch = item / IPB;
  const int r     = IPB - 1 - (item % IPB);

  int qt, kvlo, kvhi, slot;
  if (mode == 2) {
    if (r < 16)       { qt = r;             kvlo = 0;    kvhi = 32 * qt + 32;             slot = -1; }
    else if (r < 64)  { qt = r;             kvlo = 0;    kvhi = 512;                      slot = batch * 144 + (r - 16); }
    else if (r < 112) { qt = 16 + (r - 64); kvlo = 512;  kvhi = imin(1024, 32 * qt + 32); slot = batch * 144 + (r - 16); }
    else if (r < 144) { qt = 32 + (r - 112); kvlo = 1024; kvhi = imin(1536, 32 * qt + 32); slot = batch * 144 + (r - 16); }
    else              { qt = 48 + (r - 144); kvlo = 1536; kvhi = 32 * qt + 32;            slot = batch * 144 + (r - 16); }
  } else if (mode == 1) {
    if (r < 32)       { qt = r;             kvlo = 0;    kvhi = 32 * qt + 32;  slot = -1; }
    else if (r < 64)  { qt = 32 + (r - 32); kvlo = 0;    kvhi = 1024;          slot = batch * 64 + (r - 32); }
    else              { qt = 32 + (r - 64); kvlo = 1024; kvhi = 32 * qt + 32;  slot = batch * 64 + (r - 32); }
  } else {
    qt = r; kvlo = 0; kvhi = 32 * qt + 32; slot = -1;
  }

  const int q0 = qt * QBLK;
  const size_t boff = (size_t)batch * SEQ * DIM;

  __shared__ __align__(16) unsigned short Qs[QBLK * 1024];   // 64 KB swizzled
  __shared__ __align__(16) unsigned short Pl[QBLK * KVBLK];  // 8 KB swizzled
  __shared__ float pmaxT[QBLK][12];
  __shared__ float psumT[QBLK][12];

  // ---- stage Q: fp32 -> bf16 LDS, 16B-slot XOR swizzle (slot ^ (row&7)) ----
  {
    const int row = tid >> 4;          // 0..31
    const int s0  = tid & 15;
    const float* qrow = Qf + boff + (size_t)(q0 + row) * DIM;
#pragma unroll
    for (int k = 0; k < 8; ++k) {
      const int slot2 = s0 + 16 * k;   // 128 slots of 8 bf16
      f32x4 a = *(const f32x4*)(qrow + slot2 * 8);
      f32x4 b = *(const f32x4*)(qrow + slot2 * 8 + 4);
      u16x8 pk;
#pragma unroll
      for (int j = 0; j < 4; ++j) { pk[j] = f2bf(a[j]); pk[4 + j] = f2bf(b[j]); }
      *(u16x8*)(Qs + row * 1024 + (slot2 ^ (row & 7)) * 8) = pk;
    }
  }

  const f32x4 zero4 = {0.f, 0.f, 0.f, 0.f};
  f32x4 o_acc[8][2];
#pragma unroll
  for (int mt = 0; mt < 8; ++mt)
#pragma unroll
    for (int nt = 0; nt < 2; ++nt) o_acc[mt][nt] = zero4;

  float m_reg[2] = {-1e30f, -1e30f};
  float l_reg[2] = {0.f, 0.f};

  const int ntiles = (kvhi - kvlo + KVBLK - 1) >> 7;
  // per-lane K base: panel (kv0>>4)+wv, unit row i16 -> +i16*8
  const unsigned short* kb = Kp + boff + (size_t)wv * KPAN + i16 * 8;
  // per-lane V base: d-row (wv*128 + i16), kv g*8
  const unsigned short* vb = Vp + boff + (size_t)(wv * 128 + i16) * 32 + g * 8;

  __syncthreads();   // Q visible

  for (int t = 0; t < ntiles; ++t) {
    const int kv0 = kvlo + t * KVBLK;
    const unsigned short* kt = kb + (size_t)(kv0 >> 4) * KPAN;  // this strip's panel
    const size_t vt0 = (size_t)(kv0 >> 5) * PAN;                // V panel base

    f32x4 sacc[2];
    sacc[0] = zero4; sacc[1] = zero4;
    bf16x8 vV0[8], vV1[8], vV2[8], vV3[8];

    // ---- QK^T: 8 phases, K frags direct global->reg (coalesced) ----
#pragma unroll
    for (int c = 0; c < 8; ++c) {
      if (c == 0) {   // issue V frags kc0,kc1 early (hide under QK)
#pragma unroll
        for (int mt = 0; mt < 8; ++mt) {
          vV0[mt] = __builtin_bit_cast(bf16x8,
              *(const u16x8*)(vb + vt0 + (size_t)mt * 512));
          vV1[mt] = __builtin_bit_cast(bf16x8,
              *(const u16x8*)(vb + vt0 + PAN + (size_t)mt * 512));
        }
      }
      const unsigned short* qrb0 = Qs + (0 * 16 + i16) * 1024;
      const unsigned short* qrb1 = Qs + (1 * 16 + i16) * 1024;
      bf16x8 kf[4], qf0[4], qf1[4];
#pragma unroll
      for (int kk = 0; kk < 4; ++kk) {
        kf[kk]  = __builtin_bit_cast(bf16x8,
            *(const u16x8*)(kt + (size_t)(c * 16 + kk * 4 + g) * 128));
        qf0[kk] = __builtin_bit_cast(bf16x8, *(const u16x8*)(qrb0 + ((c * 16 + kk * 4 + g) ^ swz) * 8));
        qf1[kk] = __builtin_bit_cast(bf16x8, *(const u16x8*)(qrb1 + ((c * 16 + kk * 4 + g) ^ swz) * 8));
      }
      __builtin_amdgcn_s_setprio(1);
#pragma unroll
      for (int kk = 0; kk < 4; ++kk) {
        sacc[0] = __builtin_amdgcn_mfma_f32_16x16x32_bf16(kf[kk], qf0[kk], sacc[0], 0, 0, 0);
        sacc[1] = __builtin_amdgcn_mfma_f32_16x16x32_bf16(kf[kk], qf1[kk], sacc[1], 0, 0, 0);
      }
      __builtin_amdgcn_s_setprio(0);
    }

    // ---- softmax: mask+scale, strip reduce, cross-wave combine ----
    float pm[2];
#pragma unroll
    for (int nt = 0; nt < 2; ++nt) {
      const int qg = q0 + nt * 16 + i16;
      const int kvbase = kv0 + wv * 16 + g * 4;
#pragma unroll
      for (int j = 0; j < 4; ++j) {
        const bool valid = (kvbase + j) <= qg;
        sacc[nt][j] = valid ? sacc[nt][j] * 0.03125f : -1e30f;
      }
      float v = fmaxf(fmaxf(sacc[nt][0], sacc[nt][1]), fmaxf(sacc[nt][2], sacc[nt][3]));
      v = fmaxf(v, __shfl_xor(v, 16));
      v = fmaxf(v, __shfl_xor(v, 32));
      pm[nt] = v;
    }
    if (lane < 32) pmaxT[(lane >> 4) * 16 + (lane & 15)][wv] = (lane < 16) ? pm[0] : pm[1];
    __syncthreads();   // A: pmax partials visible

    float alpha[2];
#pragma unroll
    for (int nt = 0; nt < 2; ++nt) {
      const float* pr = &pmaxT[nt * 16 + i16][0];
      f32x4 a = *(const f32x4*)(pr);
      f32x4 b = *(const f32x4*)(pr + 4);
      float mx = fmaxf(fmaxf(fmaxf(a[0], a[1]), fmaxf(a[2], a[3])),
                       fmaxf(fmaxf(b[0], b[1]), fmaxf(b[2], b[3])));
      const float m_new = fmaxf(m_reg[nt], mx);
      alpha[nt] = __expf(m_reg[nt] - m_new);
      m_reg[nt] = m_new;

      float ps = 0.f;
      u16x4 pw;
#pragma unroll
      for (int j = 0; j < 4; ++j) {
        const float p = __expf(sacc[nt][j] - m_new);   // masked -> 0
        ps += p;
        pw[j] = f2bf(p);
      }
      const int pslot = (wv * 2 + (g >> 1)) ^ swz;
      *(u16x4*)(Pl + (nt * 16 + i16) * 128 + pslot * 8 + (g & 1) * 4) = pw;
      ps += __shfl_xor(ps, 16);
      ps += __shfl_xor(ps, 32);
      pm[nt] = ps;
    }
    if (lane < 32) psumT[(lane >> 4) * 16 + (lane & 15)][wv] = (lane < 16) ? pm[0] : pm[1];
    __syncthreads();   // B: P + psum visible

    // ---- l update + O rescale ----
#pragma unroll
    for (int nt = 0; nt < 2; ++nt) {
      const float* pr = &psumT[nt * 16 + i16][0];
      f32x4 a = *(const f32x4*)(pr);
      f32x4 b = *(const f32x4*)(pr + 4);
      const float st = (a[0] + a[1] + a[2] + a[3]) + (b[0] + b[1] + b[2] + b[3]);
      l_reg[nt] = alpha[nt] * l_reg[nt] + st;
#pragma unroll
      for (int mt = 0; mt < 8; ++mt)
#pragma unroll
        for (int j = 0; j < 4; ++j) o_acc[mt][nt][j] *= alpha[nt];
    }

#define PV_STEP(KC, VREG)                                                      \
    do {                                                                        \
      bf16x8 pfa = __builtin_bit_cast(bf16x8, *(const u16x8*)(                  \
          Pl + (0 * 16 + i16) * 128 + (((KC) * 4 + g) ^ swz) * 8));             \
      bf16x8 pfb = __builtin_bit_cast(bf16x8, *(const u16x8*)(                  \
          Pl + (1 * 16 + i16) * 128 + (((KC) * 4 + g) ^ swz) * 8));             \
      __builtin_amdgcn_s_setprio(1);                                            \
      _Pragma("unroll")                                                         \
      for (int mt = 0; mt < 8; ++mt) {                                          \
        o_acc[mt][0] = __builtin_amdgcn_mfma_f32_16x16x32_bf16(VREG[mt], pfa,   \
                                                               o_acc[mt][0], 0, 0, 0); \
        o_acc[mt][1] = __builtin_amdgcn_mfma_f32_16x16x32_bf16(VREG[mt], pfb,   \
                                                               o_acc[mt][1], 0, 0, 0); \
      }                                                                         \
      __builtin_amdgcn_s_setprio(0);                                            \
    } while (0)

#pragma unroll
    for (int mt = 0; mt < 8; ++mt)   // prefetch kc2 (panel +2)
      vV2[mt] = __builtin_bit_cast(bf16x8,
          *(const u16x8*)(vb + vt0 + 2 * PAN + (size_t)mt * 512));
    PV_STEP(0, vV0);
#pragma unroll
    for (int mt = 0; mt < 8; ++mt)   // prefetch kc3 (panel +3)
      vV3[mt] = __builtin_bit_cast(bf16x8,
          *(const u16x8*)(vb + vt0 + 3 * PAN + (size_t)mt * 512));
    PV_STEP(1, vV1);
    PV_STEP(2, vV2);
    PV_STEP(3, vV3);
#undef PV_STEP

    __syncthreads();   // C: P consumed before next tile overwrites
  }

  // ---- epilogue ----
  if (slot < 0) {
#pragma unroll
    for (int nt = 0; nt < 2; ++nt) {
      const float linv = 1.f / l_reg[nt];
      const size_t qoff = boff + (size_t)(q0 + nt * 16 + i16) * DIM + wv * 128 + g * 4;
#pragma unroll
      for (int mt = 0; mt < 8; ++mt) {
        f32x4 o;
#pragma unroll
        for (int j = 0; j < 4; ++j) o[j] = o_acc[mt][nt][j] * linv;
        *(f32x4*)(Out + qoff + mt * 16) = o;
      }
    }
  } else {
    const size_t pbase = (size_t)slot * (QBLK * DIM);
#pragma unroll
    for (int nt = 0; nt < 2; ++nt) {
      const size_t qoff = pbase + (size_t)(nt * 16 + i16) * DIM + wv * 128 + g * 4;
#pragma unroll
      for (int mt = 0; mt < 8; ++mt)
        *(f32x4*)(Opart + qoff + mt * 16) = o_acc[mt][nt];
    }
    if (wv == 0 && lane < 16) {
#pragma unroll
      for (int nt = 0; nt < 2; ++nt) {
        Ml[(size_t)slot * 64 + (nt * 16 + lane) * 2 + 0] = m_reg[nt];
        Ml[(size_t)slot * 64 + (nt * 16 + lane) * 2 + 1] = l_reg[nt];
      }
    }
  }
}

// Deterministic flash-merge of <=4 partials per (batch, qtile).
__global__ void combine_kernel(const float* __restrict__ Opart,
                               const float* __restrict__ Ml,
                               float* __restrict__ Out, int mode) {
  const int NT  = (mode == 2) ? 48 : 32;
  const int qt0 = (mode == 2) ? 16 : 32;
  const int b   = blockIdx.x / NT;
  const int qt  = qt0 + blockIdx.x % NT;
  const int n   = (mode == 2) ? ((qt >> 4) + 1) : 2;

  int slots[4];
  if (mode == 2) {
    slots[0] = b * 144 + (qt - 16);
    slots[1] = b * 144 + 48 + (qt - 16);
    slots[2] = b * 144 + 96 + (qt - 32);
    slots[3] = b * 144 + 128 + (qt - 48);
  } else {
    slots[0] = b * 64 + (qt - 32);
    slots[1] = b * 64 + 32 + (qt - 32);
    slots[2] = slots[3] = 0;
  }

  __shared__ float wsh[4][32];
  __shared__ float lsh[32];
  const int t = threadIdx.x;   // 256
  if (t < 32) {
    float mc[4], lc[4];
    float m = -1e30f;
    for (int c = 0; c < n; ++c) {
      mc[c] = Ml[(size_t)slots[c] * 64 + t * 2 + 0];
      lc[c] = Ml[(size_t)slots[c] * 64 + t * 2 + 1];
      m = fmaxf(m, mc[c]);
    }
    float l = 0.f;
    for (int c = 0; c < n; ++c) {
      const float w = __expf(mc[c] - m);
      wsh[c][t] = w;
      l += w * lc[c];
    }
    lsh[t] = 1.f / l;
  }
  __syncthreads();

  const size_t obase = ((size_t)b * SEQ + (size_t)qt * 32) * DIM;
  const int d = t * 4;
  for (int q = 0; q < 32; ++q) {
    f32x4 acc = {0.f, 0.f, 0.f, 0.f};
    for (int c = 0; c < n; ++c) {
      f32x4 x = *(const f32x4*)(Opart + (size_t)slots[c] * (QBLK * DIM) + (size_t)q * DIM + d);
      const float w = wsh[c][q];
#pragma unroll
      for (int j = 0; j < 4; ++j) acc[j] += w * x[j];
    }
    const float li = lsh[q];
    f32x4 o;
#pragma unroll
    for (int j = 0; j < 4; ++j) o[j] = acc[j] * li;
    *(f32x4*)(Out + obase + (size_t)q * DIM + d) = o;
  }
}

// Emergency fallback - correct, not fast.
__global__ void attn_naive(const float* __restrict__ Q, const float* __restrict__ K,
                           const float* __restrict__ V, float* __restrict__ Out) {
  const int b = blockIdx.y, q = blockIdx.x;
  const int t = threadIdx.x;
  __shared__ float qs[DIM];
  __shared__ float sc[SEQ];
  __shared__ float red[2];
  const size_t boff = (size_t)b * SEQ * DIM;
  for (int d = t; d < DIM; d += 256) qs[d] = Q[boff + (size_t)q * DIM + d];
  __syncthreads();
  const int kvmax = q + 1;
  for (int kv = t; kv < kvmax; kv += 256) {
    const float* kr = K + boff + (size_t)kv * DIM;
    float s = 0.f;
    for (int d = 0; d < DIM; ++d) s += qs[d] * kr[d];
    sc[kv] = s * 0.03125f;
  }
  __syncthreads();
  if (t == 0) {
    float m = -1e30f;
    for (int kv = 0; kv < kvmax; ++kv) m = fmaxf(m, sc[kv]);
    red[0] = m;
  }
  __syncthreads();
  const float m = red[0];
  for (int kv = t; kv < kvmax; kv += 256) sc[kv] = __expf(sc[kv] - m);
  __syncthreads();
  if (t == 0) {
    float l = 0.f;
    for (int kv = 0; kv < kvmax; ++kv) l += sc[kv];
    red[1] = l;
  }
  __syncthreads();
  const float linv = 1.f / red[1];
  for (int d = t; d < DIM; d += 256) {
    float o = 0.f;
    for (int kv = 0; kv < kvmax; ++kv) o += sc[kv] * V[boff + (size_t)kv * DIM + d];
    Out[boff + (size_t)q * DIM + d] = o * linv;
  }
}

extern "C" void kernel_launch(void* const* d_in, const int* in_sizes, int n_in,
                              void* d_out, int out_size, void* d_ws, size_t ws_size,
                              hipStream_t stream) {
  (void)in_sizes; (void)n_in; (void)out_size;
  const float* Q = (const float*)d_in[0];
  const float* K = (const float*)d_in[1];
  const float* V = (const float*)d_in[2];
  float* Out = (float*)d_out;

  const size_t nelem   = (size_t)B_SZ * SEQ * DIM;            // 8.4M / tensor
  const size_t bf_b    = nelem * sizeof(unsigned short);      // 16 MB
  const size_t ml_b    = (size_t)640 * 64 * sizeof(float);    // 160 KB (max)
  const size_t part1_b = (size_t)256 * QBLK * DIM * sizeof(float);   // 32 MB
  const size_t part2_b = (size_t)576 * QBLK * DIM * sizeof(float);   // 72 MB

  const size_t need0 = 2 * bf_b;
  const size_t need1 = 2 * bf_b + ml_b + part1_b;
  const size_t need2 = 2 * bf_b + ml_b + part2_b;

  const int mode = (ws_size >= need2) ? 2 : (ws_size >= need1) ? 1
                   : (ws_size >= need0) ? 0 : -1;

  if (mode < 0) {
    hipLaunchKernelGGL(attn_naive, dim3(SEQ, B_SZ), dim3(256), 0, stream, Q, K, V, Out);
    return;
  }

  unsigned short* Kp = (unsigned short*)d_ws;
  unsigned short* Vp = Kp + nelem;
  float* Ml    = (float*)(Vp + nelem);
  float* Opart = Ml + 640 * 64;

  hipLaunchKernelGGL(transpose_k_kernel, dim3(DIM / 128, SEQ / 16, B_SZ), dim3(256),
                     0, stream, K, Kp);
  hipLaunchKernelGGL(transpose_v_kernel, dim3(DIM / 32, SEQ / 32, B_SZ), dim3(256),
                     0, stream, V, Vp);

  const int grid = (mode == 2) ? 640 : (mode == 1) ? 384 : 256;
  hipLaunchKernelGGL(attn_part, dim3(grid), dim3(NWAVES * 64), 0, stream,
                     Q, Kp, Vp, Out, Opart, Ml, mode);

  if (mode >= 1) {
    const int cgrid = (mode == 2) ? (B_SZ * 48) : (B_SZ * 32);
    hipLaunchKernelGGL(combine_kernel, dim3(cgrid), dim3(256), 0, stream,
                       Opart, Ml, Out, mode);
  }
}

// Round 13
// 124.854 us; speedup vs baseline: 3.4947x; 1.2178x over previous
//
#include <hip/hip_runtime.h>
#include <stdint.h>

// Causal attention, B=4, SQ=SK=2048, D=1024, fp32 in/out, bf16 MFMA compute.
// R13 = R12 with (a) redundant barrier C removed (cross-tile hazards already
//      ordered by next tile's barriers A/B -> fast waves pipeline into next
//      QK^T while slow waves finish PV), (b) combine kernel parallelized.
// Layouts: Kp[b][kv/16][d/8][kv%16][8d]  (A-frag load = 1KB/wave contiguous)
//          Vp[b][sk/32][d][sk%32]        (PV frag load = 1KB/wave contiguous)

#define B_SZ 4
#define SEQ 2048
#define DIM 1024
#define QBLK 32
#define KVBLK 128
#define NWAVES 8
#define PAN  ((size_t)DIM * 32)   // elems per 32-kv V panel
#define KPAN ((size_t)DIM * 16)   // elems per 16-kv K panel

typedef __bf16 bf16x8 __attribute__((ext_vector_type(8)));
typedef unsigned short u16x8 __attribute__((ext_vector_type(8)));
typedef unsigned short u16x4 __attribute__((ext_vector_type(4)));
typedef float f32x4 __attribute__((ext_vector_type(4)));

__device__ __forceinline__ unsigned short f2bf(float f) {
  union { float f; uint32_t u; } c; c.f = f;
  uint32_t u = c.u;
  u += 0x7FFFu + ((u >> 16) & 1u);   // RNE
  return (unsigned short)(u >> 16);
}

// K[b][kv][d] fp32 -> Kp[b][kv/16][d/8][kv%16][8] bf16
__global__ void transpose_k_kernel(const float* __restrict__ in,
                                   unsigned short* __restrict__ out) {
  const int b   = blockIdx.z;
  const int kv0 = blockIdx.y * 16;
  const int d0  = blockIdx.x * 128;
  const int t   = threadIdx.x;          // 256
  const int kvl = t >> 4;               // 0..15
  const int uu  = t & 15;               // 0..15 d-units
  const int d   = d0 + uu * 8;
  const float* src = in + (size_t)b * SEQ * DIM + (size_t)(kv0 + kvl) * DIM + d;
  f32x4 a = *(const f32x4*)(src);
  f32x4 c = *(const f32x4*)(src + 4);
  u16x8 pk;
#pragma unroll
  for (int j = 0; j < 4; ++j) { pk[j] = f2bf(a[j]); pk[4 + j] = f2bf(c[j]); }
  *(u16x8*)(out + (size_t)b * SEQ * DIM + (size_t)blockIdx.y * KPAN
            + (size_t)(d >> 3) * 128 + kvl * 8) = pk;
}

// V[b][sk][d] fp32 -> Vp[b][sk/32][d][sk%32] bf16 (panel-transposed)
__global__ void transpose_v_kernel(const float* __restrict__ in,
                                   unsigned short* __restrict__ out) {
  __shared__ unsigned short tile[32][33];
  const int b  = blockIdx.z;
  const int s0 = blockIdx.y * 32;
  const int d0 = blockIdx.x * 32;
  const int t  = threadIdx.x;
  const int r  = t >> 3;
  const int c4 = (t & 7) * 4;
  const size_t ibase = (size_t)b * SEQ * DIM;
  const size_t obase = (size_t)b * DIM * SEQ;

  f32x4 v = *(const f32x4*)(in + ibase + (size_t)(s0 + r) * DIM + d0 + c4);
#pragma unroll
  for (int j = 0; j < 4; ++j) tile[r][c4 + j] = f2bf(v[j]);
  __syncthreads();
  u16x4 o;
#pragma unroll
  for (int j = 0; j < 4; ++j) o[j] = tile[c4 + j][r];
  *(u16x4*)(out + obase + (size_t)(s0 >> 5) * PAN + (size_t)(d0 + r) * 32 + c4) = o;
}

__device__ __forceinline__ int imin(int a, int b) { return a < b ? a : b; }

__global__ __launch_bounds__(512, 2) void attn_part(
    const float* __restrict__ Qf, const unsigned short* __restrict__ Kp,
    const unsigned short* __restrict__ Vp, float* __restrict__ Out,
    float* __restrict__ Opart, float* __restrict__ Ml, int mode) {
  const int tid  = threadIdx.x;
  const int lane = tid & 63;
  const int wv   = tid >> 6;        // 0..7: kv strip (QK) and 128-wide D slice (PV)
  const int g    = lane >> 4;       // 0..3
  const int i16  = lane & 15;
  const int swz  = i16 & 7;

  // ---- work-item decode: chunk-major, XCD-affine, heavy-first ----
  const int IPX = (mode == 2) ? 80 : (mode == 1) ? 48 : 32;
  const int IPB = (mode == 2) ? 160 : (mode == 1) ? 96 : 64;
  const int item  = (blockIdx.x & 7) * IPX + (blockIdx.x >> 3);
  const int batch = item / IPB;
  const int r     = IPB - 1 - (item % IPB);

  int qt, kvlo, kvhi, slot;
  if (mode == 2) {
    if (r < 16)       { qt = r;             kvlo = 0;    kvhi = 32 * qt + 32;             slot = -1; }
    else if (r < 64)  { qt = r;             kvlo = 0;    kvhi = 512;                      slot = batch * 144 + (r - 16); }
    else if (r < 112) { qt = 16 + (r - 64); kvlo = 512;  kvhi = imin(1024, 32 * qt + 32); slot = batch * 144 + (r - 16); }
    else if (r < 144) { qt = 32 + (r - 112); kvlo = 1024; kvhi = imin(1536, 32 * qt + 32); slot = batch * 144 + (r - 16); }
    else              { qt = 48 + (r - 144); kvlo = 1536; kvhi = 32 * qt + 32;            slot = batch * 144 + (r - 16); }
  } else if (mode == 1) {
    if (r < 32)       { qt = r;             kvlo = 0;    kvhi = 32 * qt + 32;  slot = -1; }
    else if (r < 64)  { qt = 32 + (r - 32); kvlo = 0;    kvhi = 1024;          slot = batch * 64 + (r - 32); }
    else              { qt = 32 + (r - 64); kvlo = 1024; kvhi = 32 * qt + 32;  slot = batch * 64 + (r - 32); }
  } else {
    qt = r; kvlo = 0; kvhi = 32 * qt + 32; slot = -1;
  }

  const int q0 = qt * QBLK;
  const size_t boff = (size_t)batch * SEQ * DIM;

  __shared__ __align__(16) unsigned short Qs[QBLK * 1024];   // 64 KB swizzled
  __shared__ __align__(16) unsigned short Pl[QBLK * KVBLK];  // 8 KB swizzled
  __shared__ float pmaxT[QBLK][12];
  __shared__ float psumT[QBLK][12];

  // ---- stage Q: fp32 -> bf16 LDS, 16B-slot XOR swizzle (slot ^ (row&7)) ----
  {
    const int row = tid >> 4;          // 0..31
    const int s0  = tid & 15;
    const float* qrow = Qf + boff + (size_t)(q0 + row) * DIM;
#pragma unroll
    for (int k = 0; k < 8; ++k) {
      const int slot2 = s0 + 16 * k;   // 128 slots of 8 bf16
      f32x4 a = *(const f32x4*)(qrow + slot2 * 8);
      f32x4 b = *(const f32x4*)(qrow + slot2 * 8 + 4);
      u16x8 pk;
#pragma unroll
      for (int j = 0; j < 4; ++j) { pk[j] = f2bf(a[j]); pk[4 + j] = f2bf(b[j]); }
      *(u16x8*)(Qs + row * 1024 + (slot2 ^ (row & 7)) * 8) = pk;
    }
  }

  const f32x4 zero4 = {0.f, 0.f, 0.f, 0.f};
  f32x4 o_acc[8][2];
#pragma unroll
  for (int mt = 0; mt < 8; ++mt)
#pragma unroll
    for (int nt = 0; nt < 2; ++nt) o_acc[mt][nt] = zero4;

  float m_reg[2] = {-1e30f, -1e30f};
  float l_reg[2] = {0.f, 0.f};

  const int ntiles = (kvhi - kvlo + KVBLK - 1) >> 7;
  // per-lane K base: panel (kv0>>4)+wv, unit row i16 -> +i16*8
  const unsigned short* kb = Kp + boff + (size_t)wv * KPAN + i16 * 8;
  // per-lane V base: d-row (wv*128 + i16), kv g*8
  const unsigned short* vb = Vp + boff + (size_t)(wv * 128 + i16) * 32 + g * 8;

  __syncthreads();   // Q visible

  for (int t = 0; t < ntiles; ++t) {
    const int kv0 = kvlo + t * KVBLK;
    const unsigned short* kt = kb + (size_t)(kv0 >> 4) * KPAN;  // this strip's panel
    const size_t vt0 = (size_t)(kv0 >> 5) * PAN;                // V panel base

    f32x4 sacc[2];
    sacc[0] = zero4; sacc[1] = zero4;
    bf16x8 vV0[8], vV1[8], vV2[8], vV3[8];

    // ---- QK^T: 8 phases, K frags direct global->reg (coalesced) ----
#pragma unroll
    for (int c = 0; c < 8; ++c) {
      if (c == 0) {   // issue V frags kc0,kc1 early (hide under QK)
#pragma unroll
        for (int mt = 0; mt < 8; ++mt) {
          vV0[mt] = __builtin_bit_cast(bf16x8,
              *(const u16x8*)(vb + vt0 + (size_t)mt * 512));
          vV1[mt] = __builtin_bit_cast(bf16x8,
              *(const u16x8*)(vb + vt0 + PAN + (size_t)mt * 512));
        }
      }
      const unsigned short* qrb0 = Qs + (0 * 16 + i16) * 1024;
      const unsigned short* qrb1 = Qs + (1 * 16 + i16) * 1024;
      bf16x8 kf[4], qf0[4], qf1[4];
#pragma unroll
      for (int kk = 0; kk < 4; ++kk) {
        kf[kk]  = __builtin_bit_cast(bf16x8,
            *(const u16x8*)(kt + (size_t)(c * 16 + kk * 4 + g) * 128));
        qf0[kk] = __builtin_bit_cast(bf16x8, *(const u16x8*)(qrb0 + ((c * 16 + kk * 4 + g) ^ swz) * 8));
        qf1[kk] = __builtin_bit_cast(bf16x8, *(const u16x8*)(qrb1 + ((c * 16 + kk * 4 + g) ^ swz) * 8));
      }
      __builtin_amdgcn_s_setprio(1);
#pragma unroll
      for (int kk = 0; kk < 4; ++kk) {
        sacc[0] = __builtin_amdgcn_mfma_f32_16x16x32_bf16(kf[kk], qf0[kk], sacc[0], 0, 0, 0);
        sacc[1] = __builtin_amdgcn_mfma_f32_16x16x32_bf16(kf[kk], qf1[kk], sacc[1], 0, 0, 0);
      }
      __builtin_amdgcn_s_setprio(0);
    }

    // ---- softmax: mask+scale, strip reduce, cross-wave combine ----
    float pm[2];
#pragma unroll
    for (int nt = 0; nt < 2; ++nt) {
      const int qg = q0 + nt * 16 + i16;
      const int kvbase = kv0 + wv * 16 + g * 4;
#pragma unroll
      for (int j = 0; j < 4; ++j) {
        const bool valid = (kvbase + j) <= qg;
        sacc[nt][j] = valid ? sacc[nt][j] * 0.03125f : -1e30f;
      }
      float v = fmaxf(fmaxf(sacc[nt][0], sacc[nt][1]), fmaxf(sacc[nt][2], sacc[nt][3]));
      v = fmaxf(v, __shfl_xor(v, 16));
      v = fmaxf(v, __shfl_xor(v, 32));
      pm[nt] = v;
    }
    if (lane < 32) pmaxT[(lane >> 4) * 16 + (lane & 15)][wv] = (lane < 16) ? pm[0] : pm[1];
    __syncthreads();   // A: pmax partials visible

    float alpha[2];
#pragma unroll
    for (int nt = 0; nt < 2; ++nt) {
      const float* pr = &pmaxT[nt * 16 + i16][0];
      f32x4 a = *(const f32x4*)(pr);
      f32x4 b = *(const f32x4*)(pr + 4);
      float mx = fmaxf(fmaxf(fmaxf(a[0], a[1]), fmaxf(a[2], a[3])),
                       fmaxf(fmaxf(b[0], b[1]), fmaxf(b[2], b[3])));
      const float m_new = fmaxf(m_reg[nt], mx);
      alpha[nt] = __expf(m_reg[nt] - m_new);
      m_reg[nt] = m_new;

      float ps = 0.f;
      u16x4 pw;
#pragma unroll
      for (int j = 0; j < 4; ++j) {
        const float p = __expf(sacc[nt][j] - m_new);   // masked -> 0
        ps += p;
        pw[j] = f2bf(p);
      }
      const int pslot = (wv * 2 + (g >> 1)) ^ swz;
      *(u16x4*)(Pl + (nt * 16 + i16) * 128 + pslot * 8 + (g & 1) * 4) = pw;
      ps += __shfl_xor(ps, 16);
      ps += __shfl_xor(ps, 32);
      pm[nt] = ps;
    }
    if (lane < 32) psumT[(lane >> 4) * 16 + (lane & 15)][wv] = (lane < 16) ? pm[0] : pm[1];
    __syncthreads();   // B: P + psum visible

    // ---- l update + O rescale ----
#pragma unroll
    for (int nt = 0; nt < 2; ++nt) {
      const float* pr = &psumT[nt * 16 + i16][0];
      f32x4 a = *(const f32x4*)(pr);
      f32x4 b = *(const f32x4*)(pr + 4);
      const float st = (a[0] + a[1] + a[2] + a[3]) + (b[0] + b[1] + b[2] + b[3]);
      l_reg[nt] = alpha[nt] * l_reg[nt] + st;
#pragma unroll
      for (int mt = 0; mt < 8; ++mt)
#pragma unroll
        for (int j = 0; j < 4; ++j) o_acc[mt][nt][j] *= alpha[nt];
    }

#define PV_STEP(KC, VREG)                                                      \
    do {                                                                        \
      bf16x8 pfa = __builtin_bit_cast(bf16x8, *(const u16x8*)(                  \
          Pl + (0 * 16 + i16) * 128 + (((KC) * 4 + g) ^ swz) * 8));             \
      bf16x8 pfb = __builtin_bit_cast(bf16x8, *(const u16x8*)(                  \
          Pl + (1 * 16 + i16) * 128 + (((KC) * 4 + g) ^ swz) * 8));             \
      __builtin_amdgcn_s_setprio(1);                                            \
      _Pragma("unroll")                                                         \
      for (int mt = 0; mt < 8; ++mt) {                                          \
        o_acc[mt][0] = __builtin_amdgcn_mfma_f32_16x16x32_bf16(VREG[mt], pfa,   \
                                                               o_acc[mt][0], 0, 0, 0); \
        o_acc[mt][1] = __builtin_amdgcn_mfma_f32_16x16x32_bf16(VREG[mt], pfb,   \
                                                               o_acc[mt][1], 0, 0, 0); \
      }                                                                         \
      __builtin_amdgcn_s_setprio(0);                                            \
    } while (0)

#pragma unroll
    for (int mt = 0; mt < 8; ++mt)   // prefetch kc2 (panel +2)
      vV2[mt] = __builtin_bit_cast(bf16x8,
          *(const u16x8*)(vb + vt0 + 2 * PAN + (size_t)mt * 512));
    PV_STEP(0, vV0);
#pragma unroll
    for (int mt = 0; mt < 8; ++mt)   // prefetch kc3 (panel +3)
      vV3[mt] = __builtin_bit_cast(bf16x8,
          *(const u16x8*)(vb + vt0 + 3 * PAN + (size_t)mt * 512));
    PV_STEP(1, vV1);
    PV_STEP(2, vV2);
    PV_STEP(3, vV3);
#undef PV_STEP
    // (barrier C removed: next tile's writes to Pl/pmaxT are ordered by its
    //  own barriers A/B -- proof in round notes. Fast waves flow into next
    //  QK^T while slow waves finish PV.)
  }

  // ---- epilogue ----
  if (slot < 0) {
#pragma unroll
    for (int nt = 0; nt < 2; ++nt) {
      const float linv = 1.f / l_reg[nt];
      const size_t qoff = boff + (size_t)(q0 + nt * 16 + i16) * DIM + wv * 128 + g * 4;
#pragma unroll
      for (int mt = 0; mt < 8; ++mt) {
        f32x4 o;
#pragma unroll
        for (int j = 0; j < 4; ++j) o[j] = o_acc[mt][nt][j] * linv;
        *(f32x4*)(Out + qoff + mt * 16) = o;
      }
    }
  } else {
    const size_t pbase = (size_t)slot * (QBLK * DIM);
#pragma unroll
    for (int nt = 0; nt < 2; ++nt) {
      const size_t qoff = pbase + (size_t)(nt * 16 + i16) * DIM + wv * 128 + g * 4;
#pragma unroll
      for (int mt = 0; mt < 8; ++mt)
        *(f32x4*)(Opart + qoff + mt * 16) = o_acc[mt][nt];
    }
    if (wv == 0 && lane < 16) {
#pragma unroll
      for (int nt = 0; nt < 2; ++nt) {
        Ml[(size_t)slot * 64 + (nt * 16 + lane) * 2 + 0] = m_reg[nt];
        Ml[(size_t)slot * 64 + (nt * 16 + lane) * 2 + 1] = l_reg[nt];
      }
    }
  }
}

// Deterministic flash-merge of <=4 partials per (batch, qtile). 1024 threads,
// flat f32x4 indexing (fully coalesced), no serial q loop.
__global__ __launch_bounds__(1024) void combine_kernel(
    const float* __restrict__ Opart, const float* __restrict__ Ml,
    float* __restrict__ Out, int mode) {
  const int NT  = (mode == 2) ? 48 : 32;
  const int qt0 = (mode == 2) ? 16 : 32;
  const int b   = blockIdx.x / NT;
  const int qt  = qt0 + blockIdx.x % NT;
  const int n   = (mode == 2) ? ((qt >> 4) + 1) : 2;

  int slots[4];
  if (mode == 2) {
    slots[0] = b * 144 + (qt - 16);
    slots[1] = b * 144 + 48 + (qt - 16);
    slots[2] = b * 144 + 96 + (qt - 32);
    slots[3] = b * 144 + 128 + (qt - 48);
  } else {
    slots[0] = b * 64 + (qt - 32);
    slots[1] = b * 64 + 32 + (qt - 32);
    slots[2] = slots[3] = 0;
  }

  __shared__ float wsh[4][32];
  __shared__ float lsh[32];
  const int t = threadIdx.x;   // 1024
  if (t < 32) {
    float mc[4], lc[4];
    float m = -1e30f;
#pragma unroll 4
    for (int c = 0; c < 4; ++c) {
      if (c < n) {
        mc[c] = Ml[(size_t)slots[c] * 64 + t * 2 + 0];
        lc[c] = Ml[(size_t)slots[c] * 64 + t * 2 + 1];
        m = fmaxf(m, mc[c]);
      }
    }
    float l = 0.f;
#pragma unroll 4
    for (int c = 0; c < 4; ++c) {
      if (c < n) {
        const float w = __expf(mc[c] - m);
        wsh[c][t] = w;
        l += w * lc[c];
      }
    }
    lsh[t] = 1.f / l;
  }
  __syncthreads();

  const size_t obase = ((size_t)b * SEQ + (size_t)qt * 32) * DIM;
  // 32 q x 1024 d = 8192 f32x4 slots; 1024 threads x 8 iters, coalesced
#pragma unroll
  for (int k = 0; k < 8; ++k) {
    const int idx = k * 1024 + t;
    const int q   = idx >> 8;          // 0..31
    const int sl  = idx & 255;         // f32x4 slot within the q row
    f32x4 acc = {0.f, 0.f, 0.f, 0.f};
#pragma unroll 4
    for (int c = 0; c < 4; ++c) {
      if (c < n) {
        f32x4 x = *(const f32x4*)(Opart + (size_t)slots[c] * (QBLK * DIM)
                                  + (size_t)q * DIM + sl * 4);
        const float w = wsh[c][q];
#pragma unroll
        for (int j = 0; j < 4; ++j) acc[j] += w * x[j];
      }
    }
    const float li = lsh[q];
    f32x4 o;
#pragma unroll
    for (int j = 0; j < 4; ++j) o[j] = acc[j] * li;
    *(f32x4*)(Out + obase + (size_t)q * DIM + sl * 4) = o;
  }
}

// Emergency fallback - correct, not fast.
__global__ void attn_naive(const float* __restrict__ Q, const float* __restrict__ K,
                           const float* __restrict__ V, float* __restrict__ Out) {
  const int b = blockIdx.y, q = blockIdx.x;
  const int t = threadIdx.x;
  __shared__ float qs[DIM];
  __shared__ float sc[SEQ];
  __shared__ float red[2];
  const size_t boff = (size_t)b * SEQ * DIM;
  for (int d = t; d < DIM; d += 256) qs[d] = Q[boff + (size_t)q * DIM + d];
  __syncthreads();
  const int kvmax = q + 1;
  for (int kv = t; kv < kvmax; kv += 256) {
    const float* kr = K + boff + (size_t)kv * DIM;
    float s = 0.f;
    for (int d = 0; d < DIM; ++d) s += qs[d] * kr[d];
    sc[kv] = s * 0.03125f;
  }
  __syncthreads();
  if (t == 0) {
    float m = -1e30f;
    for (int kv = 0; kv < kvmax; ++kv) m = fmaxf(m, sc[kv]);
    red[0] = m;
  }
  __syncthreads();
  const float m = red[0];
  for (int kv = t; kv < kvmax; kv += 256) sc[kv] = __expf(sc[kv] - m);
  __syncthreads();
  if (t == 0) {
    float l = 0.f;
    for (int kv = 0; kv < kvmax; ++kv) l += sc[kv];
    red[1] = l;
  }
  __syncthreads();
  const float linv = 1.f / red[1];
  for (int d = t; d < DIM; d += 256) {
    float o = 0.f;
    for (int kv = 0; kv < kvmax; ++kv) o += sc[kv] * V[boff + (size_t)kv * DIM + d];
    Out[boff + (size_t)q * DIM + d] = o * linv;
  }
}

extern "C" void kernel_launch(void* const* d_in, const int* in_sizes, int n_in,
                              void* d_out, int out_size, void* d_ws, size_t ws_size,
                              hipStream_t stream) {
  (void)in_sizes; (void)n_in; (void)out_size;
  const float* Q = (const float*)d_in[0];
  const float* K = (const float*)d_in[1];
  const float* V = (const float*)d_in[2];
  float* Out = (float*)d_out;

  const size_t nelem   = (size_t)B_SZ * SEQ * DIM;            // 8.4M / tensor
  const size_t bf_b    = nelem * sizeof(unsigned short);      // 16 MB
  const size_t ml_b    = (size_t)640 * 64 * sizeof(float);    // 160 KB (max)
  const size_t part1_b = (size_t)256 * QBLK * DIM * sizeof(float);   // 32 MB
  const size_t part2_b = (size_t)576 * QBLK * DIM * sizeof(float);   // 72 MB

  const size_t need0 = 2 * bf_b;
  const size_t need1 = 2 * bf_b + ml_b + part1_b;
  const size_t need2 = 2 * bf_b + ml_b + part2_b;

  const int mode = (ws_size >= need2) ? 2 : (ws_size >= need1) ? 1
                   : (ws_size >= need0) ? 0 : -1;

  if (mode < 0) {
    hipLaunchKernelGGL(attn_naive, dim3(SEQ, B_SZ), dim3(256), 0, stream, Q, K, V, Out);
    return;
  }

  unsigned short* Kp = (unsigned short*)d_ws;
  unsigned short* Vp = Kp + nelem;
  float* Ml    = (float*)(Vp + nelem);
  float* Opart = Ml + 640 * 64;

  hipLaunchKernelGGL(transpose_k_kernel, dim3(DIM / 128, SEQ / 16, B_SZ), dim3(256),
                     0, stream, K, Kp);
  hipLaunchKernelGGL(transpose_v_kernel, dim3(DIM / 32, SEQ / 32, B_SZ), dim3(256),
                     0, stream, V, Vp);

  const int grid = (mode == 2) ? 640 : (mode == 1) ? 384 : 256;
  hipLaunchKernelGGL(attn_part, dim3(grid), dim3(NWAVES * 64), 0, stream,
                     Q, Kp, Vp, Out, Opart, Ml, mode);

  if (mode >= 1) {
    const int cgrid = (mode == 2) ? (B_SZ * 48) : (B_SZ * 32);
    hipLaunchKernelGGL(combine_kernel, dim3(cgrid), dim3(1024), 0, stream,
                       Opart, Ml, Out, mode);
  }
}